// Round 3
// baseline (1350.578 us; speedup 1.0000x reference)
//
#include <hip/hip_runtime.h>
#include <math.h>

#define N_NODES 100000
#define N_EDGES 600000
#define NB_SCAN ((N_NODES + 1023) / 1024)   // 98 scan blocks of 1024

// ===========================================================================
// CSR build: counting sort of edges by dst (unchanged from round 2).
// ===========================================================================
__global__ void hist_k(const int* __restrict__ dst, int* __restrict__ counts,
                       int* __restrict__ rank)
{
    int e = blockIdx.x * 256 + threadIdx.x;
    if (e < N_EDGES) rank[e] = atomicAdd(&counts[dst[e]], 1);
}

__global__ void scan_a_k(const int* __restrict__ counts, int* __restrict__ row_ptr,
                         int* __restrict__ blockSums)
{
    __shared__ int s[256];
    const int t = threadIdx.x;
    const int base = blockIdx.x * 1024 + t * 4;
    int c[4];
#pragma unroll
    for (int j = 0; j < 4; ++j) c[j] = (base + j < N_NODES) ? counts[base + j] : 0;
    const int tot = c[0] + c[1] + c[2] + c[3];
    s[t] = tot;
    __syncthreads();
    for (int off = 1; off < 256; off <<= 1) {
        int v = (t >= off) ? s[t - off] : 0;
        __syncthreads();
        s[t] += v;
        __syncthreads();
    }
    int run = s[t] - tot;
#pragma unroll
    for (int j = 0; j < 4; ++j) {
        if (base + j < N_NODES) row_ptr[base + j] = run;
        run += c[j];
    }
    if (t == 255) blockSums[blockIdx.x] = s[255];
}

__global__ void scan_b_k(const int* __restrict__ blockSums, int* __restrict__ blockOffs)
{
    if (threadIdx.x == 0) {
        int run = 0;
        for (int b = 0; b < NB_SCAN; ++b) { blockOffs[b] = run; run += blockSums[b]; }
    }
}

__global__ void scan_c_k(int* __restrict__ row_ptr, const int* __restrict__ blockOffs)
{
    int i = blockIdx.x * 256 + threadIdx.x;
    if (i < N_NODES) row_ptr[i] += blockOffs[i >> 10];
    if (i == 0) row_ptr[N_NODES] = N_EDGES;
}

__global__ void scatter_k(const int* __restrict__ dst, const int* __restrict__ row_ptr,
                          const int* __restrict__ rank, int* __restrict__ perm)
{
    int e = blockIdx.x * 256 + threadIdx.x;
    if (e < N_EDGES) perm[row_ptr[dst[e]] + rank[e]] = e;
}

// ===========================================================================
// CSR gather-aggregation, ILP version:
//   agg[n] = sum_{e in in(n)} relu(x[src[e]] + ef[e]@We + be)
// 128 threads/node (thread = feature), 2 nodes per 256-block, grid-stride over
// nodes (amortizes the 32-reg We prologue). Edge loop unrolled x4 with
// independent load/accumulate chains so each wave keeps ~12+ global loads in
// flight (round-2 version had ~1 dependent chain -> latency-bound at 8% HBM).
// ===========================================================================
__global__ __launch_bounds__(256) void agg_csr_k(
    const float* __restrict__ x, const int* __restrict__ src, const float* __restrict__ ef,
    const int* __restrict__ row_ptr, const int* __restrict__ perm,
    const float* __restrict__ We, const float* __restrict__ be, float* __restrict__ agg)
{
    const int c    = threadIdx.x & 127;
    const int slot = threadIdx.x >> 7;

    float we[32];
#pragma unroll
    for (int d = 0; d < 32; ++d) we[d] = We[d * 128 + c];
    const float bec = be[c];

    const int nstride = gridDim.x * 2;
    for (int node = blockIdx.x * 2 + slot; node < N_NODES; node += nstride) {
        const int start = row_ptr[node];
        const int end   = row_ptr[node + 1];
        float acc = 0.f;

        int i = start;
        // ---- main: 4 edges per iteration, independent chains ----
        for (; i + 4 <= end; i += 4) {
            const int e0 = perm[i + 0];
            const int e1 = perm[i + 1];
            const int e2 = perm[i + 2];
            const int e3 = perm[i + 3];
            const int s0 = src[e0], s1 = src[e1], s2 = src[e2], s3 = src[e3];
            // x gathers: longest-latency loads, issue all 4 first
            const float x0 = x[(size_t)s0 * 128 + c];
            const float x1 = x[(size_t)s1 * 128 + c];
            const float x2 = x[(size_t)s2 * 128 + c];
            const float x3 = x[(size_t)s3 * 128 + c];

            const float4* p0 = (const float4*)(ef + (size_t)e0 * 32);
            const float4* p1 = (const float4*)(ef + (size_t)e1 * 32);
            const float4* p2 = (const float4*)(ef + (size_t)e2 * 32);
            const float4* p3 = (const float4*)(ef + (size_t)e3 * 32);
            float ed0 = bec, ed1 = bec, ed2 = bec, ed3 = bec;
#pragma unroll
            for (int d4 = 0; d4 < 8; ++d4) {
                const float4 v0 = p0[d4];
                const float4 v1 = p1[d4];
                const float4 v2 = p2[d4];
                const float4 v3 = p3[d4];
                const float w0 = we[4 * d4 + 0], w1 = we[4 * d4 + 1];
                const float w2 = we[4 * d4 + 2], w3 = we[4 * d4 + 3];
                ed0 = fmaf(v0.x, w0, ed0); ed0 = fmaf(v0.y, w1, ed0);
                ed0 = fmaf(v0.z, w2, ed0); ed0 = fmaf(v0.w, w3, ed0);
                ed1 = fmaf(v1.x, w0, ed1); ed1 = fmaf(v1.y, w1, ed1);
                ed1 = fmaf(v1.z, w2, ed1); ed1 = fmaf(v1.w, w3, ed1);
                ed2 = fmaf(v2.x, w0, ed2); ed2 = fmaf(v2.y, w1, ed2);
                ed2 = fmaf(v2.z, w2, ed2); ed2 = fmaf(v2.w, w3, ed2);
                ed3 = fmaf(v3.x, w0, ed3); ed3 = fmaf(v3.y, w1, ed3);
                ed3 = fmaf(v3.z, w2, ed3); ed3 = fmaf(v3.w, w3, ed3);
            }
            acc += fmaxf(x0 + ed0, 0.f);
            acc += fmaxf(x1 + ed1, 0.f);
            acc += fmaxf(x2 + ed2, 0.f);
            acc += fmaxf(x3 + ed3, 0.f);
        }
        // ---- remainder (<4 edges) ----
        for (; i < end; ++i) {
            const int e = perm[i];
            const int s = src[e];
            const float xv = x[(size_t)s * 128 + c];
            const float4* p = (const float4*)(ef + (size_t)e * 32);
            float ed = bec;
#pragma unroll
            for (int d4 = 0; d4 < 8; ++d4) {
                const float4 v = p[d4];
                ed = fmaf(v.x, we[4 * d4 + 0], ed);
                ed = fmaf(v.y, we[4 * d4 + 1], ed);
                ed = fmaf(v.z, we[4 * d4 + 2], ed);
                ed = fmaf(v.w, we[4 * d4 + 3], ed);
            }
            acc += fmaxf(xv + ed, 0.f);
        }
        agg[(size_t)node * 128 + c] = acc;
    }
}

// ---------------------------------------------------------------------------
// Fused 2-layer node MLP (unchanged):
//   t   = act1((xin + agg) @ Wa + ba);  out = actF(t @ Wb + bb)
// ---------------------------------------------------------------------------
template <int NOUT, bool TANH1, bool TANHF, bool ADDAGG>
__global__ __launch_bounds__(256, 4) void mlp2_k(
    const float* __restrict__ xin, const float* __restrict__ agg,
    const float* __restrict__ Wa, const float* __restrict__ ba,
    const float* __restrict__ Wb, const float* __restrict__ bb,
    float* __restrict__ out)
{
    __shared__ float hT[128][68];
    const int tid = threadIdx.x;
    const int n0  = blockIdx.x * 64;

    {
        const int mrow = tid >> 5;
        const int kq   = tid & 31;
#pragma unroll
        for (int g = 0; g < 8; ++g) {
            const int row  = g * 8 + mrow;
            const int node = n0 + row;
            float4 v = make_float4(0.f, 0.f, 0.f, 0.f);
            if (node < N_NODES) {
                v = *(const float4*)(xin + (size_t)node * 128 + kq * 4);
                if (ADDAGG) {
                    float4 a = *(const float4*)(agg + (size_t)node * 128 + kq * 4);
                    v.x += a.x; v.y += a.y; v.z += a.z; v.w += a.w;
                }
            }
            hT[kq * 4 + 0][row] = v.x;
            hT[kq * 4 + 1][row] = v.y;
            hT[kq * 4 + 2][row] = v.z;
            hT[kq * 4 + 3][row] = v.w;
        }
    }
    __syncthreads();

    const int ty4 = (tid >> 4) * 4;
    const int tx4 = (tid & 15) * 4;

    float acc[2][4][4];
#pragma unroll
    for (int p = 0; p < 2; ++p)
#pragma unroll
        for (int i = 0; i < 4; ++i)
#pragma unroll
            for (int j = 0; j < 4; ++j) acc[p][i][j] = 0.f;

#pragma unroll 4
    for (int k = 0; k < 128; ++k) {
        const float4 av = *(const float4*)&hT[k][ty4];
#pragma unroll
        for (int p = 0; p < 2; ++p) {
            const float4 bv = *(const float4*)(Wa + (size_t)k * 128 + p * 64 + tx4);
            acc[p][0][0] = fmaf(av.x, bv.x, acc[p][0][0]);
            acc[p][0][1] = fmaf(av.x, bv.y, acc[p][0][1]);
            acc[p][0][2] = fmaf(av.x, bv.z, acc[p][0][2]);
            acc[p][0][3] = fmaf(av.x, bv.w, acc[p][0][3]);
            acc[p][1][0] = fmaf(av.y, bv.x, acc[p][1][0]);
            acc[p][1][1] = fmaf(av.y, bv.y, acc[p][1][1]);
            acc[p][1][2] = fmaf(av.y, bv.z, acc[p][1][2]);
            acc[p][1][3] = fmaf(av.y, bv.w, acc[p][1][3]);
            acc[p][2][0] = fmaf(av.z, bv.x, acc[p][2][0]);
            acc[p][2][1] = fmaf(av.z, bv.y, acc[p][2][1]);
            acc[p][2][2] = fmaf(av.z, bv.z, acc[p][2][2]);
            acc[p][2][3] = fmaf(av.z, bv.w, acc[p][2][3]);
            acc[p][3][0] = fmaf(av.w, bv.x, acc[p][3][0]);
            acc[p][3][1] = fmaf(av.w, bv.y, acc[p][3][1]);
            acc[p][3][2] = fmaf(av.w, bv.z, acc[p][3][2]);
            acc[p][3][3] = fmaf(av.w, bv.w, acc[p][3][3]);
        }
    }
    __syncthreads();

#pragma unroll
    for (int p = 0; p < 2; ++p) {
        const int cb = p * 64 + tx4;
        const float4 bias = *(const float4*)(ba + cb);
        const float bj[4] = {bias.x, bias.y, bias.z, bias.w};
#pragma unroll
        for (int i = 0; i < 4; ++i) {
#pragma unroll
            for (int j = 0; j < 4; ++j) {
                float v = acc[p][i][j] + bj[j];
                v = TANH1 ? tanhf(v) : fmaxf(v, 0.f);
                hT[cb + j][ty4 + i] = v;
            }
        }
    }
    __syncthreads();

#pragma unroll
    for (int p = 0; p < NOUT / 64; ++p) {
        float a2[4][4];
#pragma unroll
        for (int i = 0; i < 4; ++i)
#pragma unroll
            for (int j = 0; j < 4; ++j) a2[i][j] = 0.f;

#pragma unroll 4
        for (int k = 0; k < 128; ++k) {
            const float4 av = *(const float4*)&hT[k][ty4];
            const float4 bv = *(const float4*)(Wb + (size_t)k * NOUT + p * 64 + tx4);
            a2[0][0] = fmaf(av.x, bv.x, a2[0][0]);
            a2[0][1] = fmaf(av.x, bv.y, a2[0][1]);
            a2[0][2] = fmaf(av.x, bv.z, a2[0][2]);
            a2[0][3] = fmaf(av.x, bv.w, a2[0][3]);
            a2[1][0] = fmaf(av.y, bv.x, a2[1][0]);
            a2[1][1] = fmaf(av.y, bv.y, a2[1][1]);
            a2[1][2] = fmaf(av.y, bv.z, a2[1][2]);
            a2[1][3] = fmaf(av.y, bv.w, a2[1][3]);
            a2[2][0] = fmaf(av.z, bv.x, a2[2][0]);
            a2[2][1] = fmaf(av.z, bv.y, a2[2][1]);
            a2[2][2] = fmaf(av.z, bv.z, a2[2][2]);
            a2[2][3] = fmaf(av.z, bv.w, a2[2][3]);
            a2[3][0] = fmaf(av.w, bv.x, a2[3][0]);
            a2[3][1] = fmaf(av.w, bv.y, a2[3][1]);
            a2[3][2] = fmaf(av.w, bv.z, a2[3][2]);
            a2[3][3] = fmaf(av.w, bv.w, a2[3][3]);
        }
        const int cb = p * 64 + tx4;
        const float4 bias = *(const float4*)(bb + cb);
#pragma unroll
        for (int i = 0; i < 4; ++i) {
            const int node = n0 + ty4 + i;
            if (node < N_NODES) {
                float4 o;
                o.x = a2[i][0] + bias.x;
                o.y = a2[i][1] + bias.y;
                o.z = a2[i][2] + bias.z;
                o.w = a2[i][3] + bias.w;
                if (TANHF) { o.x = tanhf(o.x); o.y = tanhf(o.y); o.z = tanhf(o.z); o.w = tanhf(o.w); }
                *(float4*)(out + (size_t)node * NOUT + cb) = o;
            }
        }
    }
}

// ---------------------------------------------------------------------------
extern "C" void kernel_launch(void* const* d_in, const int* in_sizes, int n_in,
                              void* d_out, int out_size, void* d_ws, size_t ws_size,
                              hipStream_t stream)
{
    const float* x   = (const float*)d_in[0];
    const int*   ei  = (const int*)  d_in[1];
    const float* ef  = (const float*)d_in[2];
    const float* We1 = (const float*)d_in[3];
    const float* be1 = (const float*)d_in[4];
    const float* W1a = (const float*)d_in[5];
    const float* b1a = (const float*)d_in[6];
    const float* W1b = (const float*)d_in[7];
    const float* b1b = (const float*)d_in[8];
    const float* We2 = (const float*)d_in[9];
    const float* be2 = (const float*)d_in[10];
    const float* W2a = (const float*)d_in[11];
    const float* b2a = (const float*)d_in[12];
    const float* W2b = (const float*)d_in[13];
    const float* b2b = (const float*)d_in[14];
    const float* Wf1 = (const float*)d_in[15];
    const float* bf1 = (const float*)d_in[16];
    const float* Wf2 = (const float*)d_in[17];
    const float* bf2 = (const float*)d_in[18];
    float* out = (float*)d_out;

    const int* src = ei;             // edge_index[0]
    const int* dst = ei + N_EDGES;   // edge_index[1]

    // ---- workspace layout ----
    float* agg     = (float*)d_ws;                      // N*128 f (written AFTER sort)
    float* h       = agg + (size_t)N_NODES * 128;       // N*128 f
    int*   row_ptr = (int*)(h + (size_t)N_NODES * 128); // N+1
    int*   perm    = row_ptr + (N_NODES + 1);           // E
    // sort temporaries overlaid on agg (dead once scatter_k completes):
    int* counts    = (int*)agg;                         // N
    int* rank      = counts + N_NODES;                  // E
    int* blockSums = rank + N_EDGES;                    // NB_SCAN
    int* blockOffs = blockSums + NB_SCAN;               // NB_SCAN

    const int mlpGrid = (N_NODES + 63) / 64;
    const int aggGrid = 8192;
    const int eGrid   = (N_EDGES + 255) / 256;
    const int nGrid   = (N_NODES + 255) / 256;

    // ---- build CSR (same work every call; edge_index is a fixed input) ----
    hipMemsetAsync(counts, 0, (size_t)N_NODES * sizeof(int), stream);
    hist_k   <<<eGrid,   256, 0, stream>>>(dst, counts, rank);
    scan_a_k <<<NB_SCAN, 256, 0, stream>>>(counts, row_ptr, blockSums);
    scan_b_k <<<1,        64, 0, stream>>>(blockSums, blockOffs);
    scan_c_k <<<nGrid,   256, 0, stream>>>(row_ptr, blockOffs);
    scatter_k<<<eGrid,   256, 0, stream>>>(dst, row_ptr, rank, perm);

    // ---- conv1 ----
    agg_csr_k<<<aggGrid, 256, 0, stream>>>(x, src, ef, row_ptr, perm, We1, be1, agg);
    mlp2_k<128, false, true, true><<<mlpGrid, 256, 0, stream>>>(x, agg, W1a, b1a, W1b, b1b, h);

    // ---- conv2 ----
    agg_csr_k<<<aggGrid, 256, 0, stream>>>(h, src, ef, row_ptr, perm, We2, be2, agg);
    mlp2_k<128, false, true, true><<<mlpGrid, 256, 0, stream>>>(h, agg, W2a, b2a, W2b, b2b, h);

    // ---- head ----
    mlp2_k<64, true, false, false><<<mlpGrid, 256, 0, stream>>>(h, nullptr, Wf1, bf1, Wf2, bf2, out);
}